// Round 3
// baseline (383.405 us; speedup 1.0000x reference)
//
#include <hip/hip_runtime.h>
#include <hip/hip_bf16.h>
#include <cmath>

#define BN_EPS 1e-6f
typedef unsigned int u32;
typedef __attribute__((ext_vector_type(8))) short short8;   // 8 bf16 (4 VGPRs)
typedef __attribute__((ext_vector_type(4))) float f32x4;    // MFMA accum

constexpr int B_    = 4;
constexpr int N_    = 16384;
constexpr int K_    = 16;
constexpr int C_IMG = 54;
constexpr int C1    = 64;     // concat channels
constexpr int CO    = 32;
constexpr int C2    = 70;
constexpr int NT    = 32;     // n per block  (2 KB contiguous per imgf channel)
constexpr int POS   = 512;    // positions (n,k) per block
constexpr int XT    = 516;    // col-major position stride in dwords (512 + 4 pad)
                              // bank(cp_row,pos) = (4*cp_row + pos) % 32:
                              //   b128 imgf writes: conflict-free (8 bank-phases)
                              //   A-frag b32 reads: 16*quad+4i+m16 -> 2-way (free)
constexpr int PPAD  = 77;     // 77 odd & coprime w/ 32 -> Phase C reads conflict-free
constexpr int NK    = N_ * K_;
constexpr int NCP   = C_IMG / 2;            // 27 channel-pairs
constexpr int ITEMS = NCP * (POS / 4);      // 27 * 128 = 3456 staging items
constexpr int ITERS = (ITEMS + 511) / 512;  // 7 (last iter: t < 384)
constexpr int TPB   = N_ / NT;              // 512 tiles per batch
constexpr int NBLK  = B_ * TPB;             // 2048 blocks = 8 XCD * 256

__device__ inline u32 pkbf(float a, float b) {      // pack 2 fp32 -> 2 bf16 (RNE), a in low half
    union { __hip_bfloat162 h; u32 u; } cv;
    cv.h = __float22bfloat162_rn(make_float2(a, b));
    return cv.u;
}

// Block = (b, 32-n tile) = 512 positions, 512 threads (8 waves).
// Phase A: bf16 concat X in LDS, col-major x[cp_row][pos]; imgf staged as
//   2 KB-contiguous dwordx4 runs per channel + conflict-free ds_write_b128.
// Phase M: wave w owns positions w*64..+63 -> 4 mtiles x 16 mfma_16x16x32_bf16,
//   BN1+ReLU in D-frag, pool over k via reg-reduce + shfl_xor(16,32) -> pooled.
// Phase C: conv2+bn2+relu (fp32) -> out (128B-contiguous stores).
// Grid: XCD-chunked bijective swizzle (2048 = 8*256) -> each XCD sweeps a
//   contiguous n-range (DRAM row locality for the 54 imgf streams).
__global__ __launch_bounds__(512, 4) void pif_mfma_kernel(
    const float* __restrict__ points, const float* __restrict__ imgf,
    const float* __restrict__ dist,   const int*   __restrict__ idx,
    const float* __restrict__ w1, const float* __restrict__ b1,
    const float* __restrict__ g1, const float* __restrict__ be1,
    const float* __restrict__ m1, const float* __restrict__ v1,
    const float* __restrict__ w2, const float* __restrict__ b2,
    const float* __restrict__ g2, const float* __restrict__ be2,
    const float* __restrict__ m2, const float* __restrict__ v2,
    float* __restrict__ out)
{
    __shared__ u32   x_lds[32 * XT];        // 66048 B, x_lds[cp_row][pos]
    __shared__ float pooled[NT][PPAD];      //  9856 B (total 75904 -> 2 blocks/CU)

    const int t = threadIdx.x;

    // XCD-chunked bijective swizzle: hw XCD = blockIdx % 8 gets contiguous chunk
    const int g   = blockIdx.x;
    const int sw  = (g & 7) * (NBLK / 8) + (g >> 3);
    const int b   = sw / TPB;
    const int n0  = (sw % TPB) * NT;

    const int lane = t & 63;
    const int w    = t >> 6;

    // ---------------- Phase A1: issue imgf loads (2 float4 per item) -------------
    // item = (channel-pair cp, position-quad q); per-wave 1 KB contiguous.
    const float* ib = imgf + (size_t)b * C_IMG * NK + n0 * K_;
    float4 va[ITERS], vb[ITERS];
    #pragma unroll
    for (int jj = 0; jj < ITERS; ++jj) {
        if (jj < ITERS - 1 || t < ITEMS - (ITERS - 1) * 512) {
            const int item = t + jj * 512;
            const int cp = item >> 7, q = item & 127;
            const float* p0 = ib + (size_t)(2 * cp) * NK + 4 * q;
            va[jj] = *(const float4*)p0;
            vb[jj] = *(const float4*)(p0 + NK);
        }
    }

    // ---------------- Phase A2: computed channels (cp rows 0..4) -----------------
    const int k = t & 15, ln = t >> 4, n = n0 + ln;
    const int   base_nk = (b * N_ + n) * K_ + k;
    const int   j  = idx[base_nk];
    const float dv = dist[base_nk];
    const int   pb = (b * N_ + n) * 3;
    const float px = points[pb], py = points[pb + 1], pz = points[pb + 2];
    const int   qb = (b * N_ + j) * 3;
    const float qx = points[qb], qy = points[qb + 1], qz = points[qb + 2];

    x_lds[0 * XT + t] = pkbf(px, py);
    x_lds[1 * XT + t] = pkbf(pz, qx);
    x_lds[2 * XT + t] = pkbf(qy, qz);
    x_lds[3 * XT + t] = pkbf(px - qx, py - qy);
    x_lds[4 * XT + t] = pkbf(pz - qz, dv);

    // ---------------- Phase A3: pack + write imgf (conflict-free b128) -----------
    #pragma unroll
    for (int jj = 0; jj < ITERS; ++jj) {
        if (jj < ITERS - 1 || t < ITEMS - (ITERS - 1) * 512) {
            const int item = t + jj * 512;
            const int cp = item >> 7, q = item & 127;
            uint4 pk;
            pk.x = pkbf(va[jj].x, vb[jj].x);
            pk.y = pkbf(va[jj].y, vb[jj].y);
            pk.z = pkbf(va[jj].z, vb[jj].z);
            pk.w = pkbf(va[jj].w, vb[jj].w);
            *(uint4*)&x_lds[(5 + cp) * XT + 4 * q] = pk;
        }
    }

    const int m16 = lane & 15, quad = lane >> 4;

    // B-frags: B[k=c][n=o], lane n=m16 reads w1[o][c..c+7] (row-major, contiguous)
    short8 bfrag[2][2];
    float  inv1v[2], add1v[2];
    #pragma unroll
    for (int ot = 0; ot < 2; ++ot) {
        const int o = ot * 16 + m16;
        #pragma unroll
        for (int kc = 0; kc < 2; ++kc) {
            const float* wr = w1 + o * C1 + kc * 32 + quad * 8;
            union { u32 u[4]; short8 v; } bf;
            bf.u[0] = pkbf(wr[0], wr[1]); bf.u[1] = pkbf(wr[2], wr[3]);
            bf.u[2] = pkbf(wr[4], wr[5]); bf.u[3] = pkbf(wr[6], wr[7]);
            bfrag[ot][kc] = bf.v;
        }
        const float iv = g1[o] * rsqrtf(v1[o] + BN_EPS);
        inv1v[ot] = iv;
        add1v[ot] = be1[o] - m1[o] * iv + b1[o] * iv;
    }

    // ep channels of pooled (max == mean == value)
    if (t < 96) {
        const int nn = t & 31, jj = t >> 5;
        const float v = points[(b * N_ + n0 + nn) * 3 + jj];
        pooled[nn][32 + jj] = v;
        pooled[nn][67 + jj] = v;
    }

    __syncthreads();

    // ---------------- Phase M: MFMA conv1 ----------------
    f32x4 acc[4][2];
    #pragma unroll
    for (int mt = 0; mt < 4; ++mt)
        #pragma unroll
        for (int ot = 0; ot < 2; ++ot)
            acc[mt][ot] = (f32x4){0.f, 0.f, 0.f, 0.f};

    #pragma unroll
    for (int mt = 0; mt < 4; ++mt) {
        const int prow = w * 64 + mt * 16 + m16;
        #pragma unroll
        for (int kc = 0; kc < 2; ++kc) {
            const u32* cb = &x_lds[(kc * 16 + quad * 4) * XT + prow];
            union { u32 u[4]; short8 v; } af;
            af.u[0] = cb[0];
            af.u[1] = cb[XT];
            af.u[2] = cb[2 * XT];
            af.u[3] = cb[3 * XT];
            acc[mt][0] = __builtin_amdgcn_mfma_f32_16x16x32_bf16(af.v, bfrag[0][kc], acc[mt][0], 0, 0, 0);
            acc[mt][1] = __builtin_amdgcn_mfma_f32_16x16x32_bf16(af.v, bfrag[1][kc], acc[mt][1], 0, 0, 0);
        }
    }

    // BN1 + ReLU + pool over k (k = quad*4 + reg within mtile)
    #pragma unroll
    for (int mt = 0; mt < 4; ++mt) {
        #pragma unroll
        for (int ot = 0; ot < 2; ++ot) {
            float mx = 0.f, sm = 0.f;
            #pragma unroll
            for (int r = 0; r < 4; ++r) {
                float hv = fmaf(acc[mt][ot][r], inv1v[ot], add1v[ot]);
                hv = fmaxf(hv, 0.f);
                mx = fmaxf(mx, hv);
                sm += hv;
            }
            mx = fmaxf(mx, __shfl_xor(mx, 16));
            mx = fmaxf(mx, __shfl_xor(mx, 32));
            sm += __shfl_xor(sm, 16);
            sm += __shfl_xor(sm, 32);
            if (quad == 0) {
                const int nn = w * 4 + mt;
                pooled[nn][ot * 16 + m16]      = mx;
                pooled[nn][35 + ot * 16 + m16] = sm * (1.f / 16.f);
            }
        }
    }
    __syncthreads();

    // ---------------- Phase C: conv2 + bn2 + relu (fp32) ----------------
    #pragma unroll
    for (int r = 0; r < 2; ++r) {
        const int nn = t & 31;
        const int o  = (t >> 5) + r * 16;
        const float* wr = w2 + o * C2;
        float a0 = 0.f, a1 = 0.f;
        #pragma unroll
        for (int c = 0; c < C2; c += 2) {
            a0 = fmaf(wr[c],     pooled[nn][c],     a0);
            a1 = fmaf(wr[c + 1], pooled[nn][c + 1], a1);
        }
        const float acc2 = a0 + a1;
        const float iv = g2[o] * rsqrtf(v2[o] + BN_EPS);
        float ov = fmaf(acc2 + b2[o], iv, be2[o] - m2[o] * iv);
        ov = fmaxf(ov, 0.f);
        out[(b * CO + o) * N_ + n0 + nn] = ov;
    }
}

extern "C" void kernel_launch(void* const* d_in, const int* in_sizes, int n_in,
                              void* d_out, int out_size, void* d_ws, size_t ws_size,
                              hipStream_t stream) {
    const float* points = (const float*)d_in[0];
    const float* imgf   = (const float*)d_in[1];
    const float* dist   = (const float*)d_in[2];
    const int*   idx    = (const int*)  d_in[3];
    const float* w1     = (const float*)d_in[4];
    const float* b1     = (const float*)d_in[5];
    const float* g1     = (const float*)d_in[6];
    const float* be1    = (const float*)d_in[7];
    const float* m1     = (const float*)d_in[8];
    const float* v1     = (const float*)d_in[9];
    const float* w2     = (const float*)d_in[10];
    const float* b2     = (const float*)d_in[11];
    const float* g2     = (const float*)d_in[12];
    const float* be2    = (const float*)d_in[13];
    const float* m2     = (const float*)d_in[14];
    const float* v2     = (const float*)d_in[15];
    float* out          = (float*)d_out;

    pif_mfma_kernel<<<NBLK, 512, 0, stream>>>(
        points, imgf, dist, idx,
        w1, b1, g1, be1, m1, v1,
        w2, b2, g2, be2, m2, v2, out);
}

// Round 4
// 362.215 us; speedup vs baseline: 1.0585x; 1.0585x over previous
//
#include <hip/hip_runtime.h>
#include <hip/hip_bf16.h>
#include <cmath>

#define BN_EPS 1e-6f
typedef unsigned int u32;
typedef __attribute__((ext_vector_type(8))) short short8;   // 8 bf16 (4 VGPRs)
typedef __attribute__((ext_vector_type(4))) float f32x4;    // MFMA accum

constexpr int B_    = 4;
constexpr int N_    = 16384;
constexpr int K_    = 16;
constexpr int C_IMG = 54;
constexpr int C1    = 64;     // concat channels (54 imgf + 10 computed, permuted)
constexpr int CO    = 32;
constexpr int C2    = 70;
constexpr int NK    = N_ * K_;

constexpr int NTB   = 64;     // n per block
constexpr int NSTEP = 8;      // steps per block
constexpr int SN    = 8;      // n per step
constexpr int SPOS  = 128;    // positions per step
constexpr int BPOS  = 1024;   // positions per block
constexpr int IST   = 260;    // imgf cp-row stride in f32 (2*128 + 4 pad): reads 2-way (free)
constexpr int CST   = 1028;   // compbuf stride in u32 (1024 + 4 pad)
constexpr int TPB   = N_ / NTB;            // 256 tiles per batch
constexpr int NBLK  = B_ * TPB;            // 1024 blocks = 8 XCD * 128

__device__ inline u32 pkbf(float a, float b) {      // pack 2 fp32 -> 2 bf16 (RNE), a in low half
    union { __hip_bfloat162 h; u32 u; } cv;
    cv.h = __float22bfloat162_rn(make_float2(a, b));
    return cv.u;
}

__device__ inline void dma16(const float* gsrc, float* ldst) {
    __builtin_amdgcn_global_load_lds(
        (const __attribute__((address_space(1))) void*)gsrc,
        (__attribute__((address_space(3))) void*)ldst, 16, 0, 0);
}

// Persistent-tile pipeline (T3+T4): block = 64 n, 8 steps of 128 pos.
// Prologue: computed channels (ep,nb,diff,dist) -> bf16 cp-rows for ALL 1024 pos
//   (idx->gather chain leaves steady state); issue step-0 imgf DMA first.
// Steady loop per step s:
//   issue DMA(s+1) -> buf[(s+1)&1]      (7 or 6 global_load_lds per wave)
//   s_waitcnt vmcnt(own IPW)            (never 0 in-loop: step-s data ready)
//   s_barrier; MFMA conv1 (K=64 = 54 imgf fp32->bf16 pack + 10 computed bf16)
//   BN1+ReLU+pool -> pooled; barrier; phase C (conv2+bn2+relu) -> out; barrier.
// Channel order permuted [imgf54 | comp10]; W1 columns permuted to match.
__global__ __launch_bounds__(256, 2) void pif_mfma_kernel(
    const float* __restrict__ points, const float* __restrict__ imgf,
    const float* __restrict__ dist,   const int*   __restrict__ idx,
    const float* __restrict__ w1, const float* __restrict__ b1,
    const float* __restrict__ g1, const float* __restrict__ be1,
    const float* __restrict__ m1, const float* __restrict__ v1,
    const float* __restrict__ w2, const float* __restrict__ b2,
    const float* __restrict__ g2, const float* __restrict__ be2,
    const float* __restrict__ m2, const float* __restrict__ v2,
    float* __restrict__ out)
{
    __shared__ float imgf_lds[2][27][IST];   // 56160 B: [buf][cp][even128|odd128|pad4]
    __shared__ u32   comp_lds[5][CST];       // 20560 B: bf16 cp-rows, whole block
    __shared__ float pooled[SN][77];         //  2464 B   (total 79184 -> 2 blocks/CU)

    const int t = threadIdx.x;

    // XCD-chunked bijective swizzle (1024 = 8*128)
    const int g   = blockIdx.x;
    const int sw  = (g & 7) * (NBLK / 8) + (g >> 3);
    const int b   = sw / TPB;
    const int bn0 = (sw % TPB) * NTB;

    const int lane = t & 63, w = t >> 6;
    const int m16 = lane & 15, quad = lane >> 4;

    // per-wave DMA channel-pair range: waves 0..2 -> 7 cps, wave 3 -> 6 cps
    const int cp0 = (w < 3) ? w * 7 : 21;
    const int ncp = (w < 3) ? 7 : 6;
    const float* ib = imgf + (size_t)b * C_IMG * NK;
    const int laneHi = lane >> 5, lane31 = lane & 31;

    // ---------------- issue DMA for step 0 immediately ----------------
    {
        const int off0 = bn0 * K_;
        for (int i = 0; i < ncp; ++i) {
            const int cp = cp0 + i;
            const float* gs = ib + (size_t)(2 * cp + laneHi) * NK + off0 + lane31 * 4;
            dma16(gs, &imgf_lds[0][cp][0]);
        }
    }

    // ---------------- prologue: computed channels for all 1024 pos ----------------
    #pragma unroll
    for (int c2 = 0; c2 < 4; ++c2) {
        const int pos = c2 * 256 + t;
        const int nl = pos >> 4, kk = pos & 15;
        const int gn = bn0 + nl;
        const int ii = (b * N_ + gn) * K_ + kk;
        const int jx = idx[ii];
        const float dvv = dist[ii];
        const int pbo = (b * N_ + gn) * 3;
        const float px = points[pbo], py = points[pbo + 1], pz = points[pbo + 2];
        const int qbo = (b * N_ + jx) * 3;
        const float qx = points[qbo], qy = points[qbo + 1], qz = points[qbo + 2];
        comp_lds[0][pos] = pkbf(px, py);
        comp_lds[1][pos] = pkbf(pz, qx);
        comp_lds[2][pos] = pkbf(qy, qz);
        comp_lds[3][pos] = pkbf(px - qx, py - qy);
        comp_lds[4][pos] = pkbf(pz - qz, dvv);
    }

    // B-frags with permuted columns: logical c<54 -> w1 col 10+c ; c>=54 -> col c-54
    short8 bfrag[2][2];
    float  inv1v[2], add1v[2];
    #pragma unroll
    for (int ot = 0; ot < 2; ++ot) {
        const int o = ot * 16 + m16;
        #pragma unroll
        for (int kc = 0; kc < 2; ++kc) {
            union { u32 u[4]; short8 v; } bf;
            #pragma unroll
            for (int i2 = 0; i2 < 4; ++i2) {
                const int lc0 = kc * 32 + quad * 8 + 2 * i2, lc1 = lc0 + 1;
                const int c0 = (lc0 < 54) ? (10 + lc0) : (lc0 - 54);
                const int c1 = (lc1 < 54) ? (10 + lc1) : (lc1 - 54);
                bf.u[i2] = pkbf(w1[o * C1 + c0], w1[o * C1 + c1]);
            }
            bfrag[ot][kc] = bf.v;
        }
        const float iv = g1[o] * rsqrtf(v1[o] + BN_EPS);
        inv1v[ot] = iv;
        add1v[ot] = be1[o] - m1[o] * iv + b1[o] * iv;
    }

    // phase-C per-thread constants (o fixed across steps)
    const int nnC = t & 7, oC = t >> 3;
    const float iv2 = g2[oC] * rsqrtf(v2[oC] + BN_EPS);
    const float ad2 = be2[oC] - m2[oC] * iv2;
    const float bb2 = b2[oC];
    const float* wr2 = w2 + oC * C2;

    __syncthreads();   // drains prologue lgkm + step-0 DMA (vmcnt 0 once, outside loop)

    // ---------------- steady loop ----------------
    #pragma unroll 1
    for (int s = 0; s < NSTEP; ++s) {
        const int bb = s & 1;

        if (s + 1 < NSTEP) {
            const int offn = (bn0 + (s + 1) * SN) * K_;
            for (int i = 0; i < ncp; ++i) {
                const int cp = cp0 + i;
                const float* gs = ib + (size_t)(2 * cp + laneHi) * NK + offn + lane31 * 4;
                dma16(gs, &imgf_lds[bb ^ 1][cp][0]);
            }
            if (w < 3) asm volatile("s_waitcnt vmcnt(7)" ::: "memory");
            else       asm volatile("s_waitcnt vmcnt(6)" ::: "memory");
        } else {
            asm volatile("s_waitcnt vmcnt(0)" ::: "memory");
        }
        __builtin_amdgcn_s_barrier();
        __builtin_amdgcn_sched_barrier(0);

        // ---- compute step s ----
        // ep rows of pooled (exact fp32; max == mean == value)
        if (t < 24) {
            const int jj = t >> 3, nn2 = t & 7;
            const float v = points[(b * N_ + bn0 + s * SN + nn2) * 3 + jj];
            pooled[nn2][32 + jj] = v;
            pooled[nn2][67 + jj] = v;
        }

        const float* Xi = &imgf_lds[bb][0][0];
        const int pco = s * SPOS;

        #pragma unroll
        for (int u = 0; u < 2; ++u) {
            const int m = 2 * w + u;           // mtile = n-row within step
            const int p = m * 16 + m16;        // position row (k = m16)
            f32x4 acc0 = (f32x4){0.f, 0.f, 0.f, 0.f};
            f32x4 acc1 = (f32x4){0.f, 0.f, 0.f, 0.f};

            #pragma unroll
            for (int kc = 0; kc < 2; ++kc) {
                union { u32 uu[4]; short8 v; } af;
                if (kc == 0) {
                    #pragma unroll
                    for (int i2 = 0; i2 < 4; ++i2) {
                        const float* cb = Xi + (quad * 4 + i2) * IST + p;
                        af.uu[i2] = pkbf(cb[0], cb[128]);
                    }
                } else {
                    if (quad < 2) {
                        #pragma unroll
                        for (int i2 = 0; i2 < 4; ++i2) {
                            const float* cb = Xi + (16 + quad * 4 + i2) * IST + p;
                            af.uu[i2] = pkbf(cb[0], cb[128]);
                        }
                    } else if (quad == 2) {
                        #pragma unroll
                        for (int i2 = 0; i2 < 3; ++i2) {
                            const float* cb = Xi + (24 + i2) * IST + p;
                            af.uu[i2] = pkbf(cb[0], cb[128]);
                        }
                        af.uu[3] = comp_lds[0][pco + p];
                    } else {
                        #pragma unroll
                        for (int i2 = 0; i2 < 4; ++i2)
                            af.uu[i2] = comp_lds[1 + i2][pco + p];
                    }
                }
                acc0 = __builtin_amdgcn_mfma_f32_16x16x32_bf16(af.v, bfrag[0][kc], acc0, 0, 0, 0);
                acc1 = __builtin_amdgcn_mfma_f32_16x16x32_bf16(af.v, bfrag[1][kc], acc1, 0, 0, 0);
            }

            // BN1 + ReLU + pool over k (k = quad*4 + reg)
            #pragma unroll
            for (int ot = 0; ot < 2; ++ot) {
                const f32x4 aa = ot ? acc1 : acc0;
                float mx = 0.f, sm = 0.f;
                #pragma unroll
                for (int r = 0; r < 4; ++r) {
                    float hv = fmaf(aa[r], inv1v[ot], add1v[ot]);
                    hv = fmaxf(hv, 0.f);
                    mx = fmaxf(mx, hv);
                    sm += hv;
                }
                mx = fmaxf(mx, __shfl_xor(mx, 16));
                mx = fmaxf(mx, __shfl_xor(mx, 32));
                sm += __shfl_xor(sm, 16);
                sm += __shfl_xor(sm, 32);
                if (quad == 0) {
                    pooled[m][ot * 16 + m16]      = mx;
                    pooled[m][35 + ot * 16 + m16] = sm * (1.f / 16.f);
                }
            }
        }

        asm volatile("s_waitcnt lgkmcnt(0)" ::: "memory");
        __builtin_amdgcn_s_barrier();
        __builtin_amdgcn_sched_barrier(0);

        // ---- phase C: conv2 + bn2 + relu for this step's 8 n ----
        {
            float a0 = 0.f, a1 = 0.f;
            #pragma unroll
            for (int c = 0; c < C2; c += 2) {
                a0 = fmaf(wr2[c],     pooled[nnC][c],     a0);
                a1 = fmaf(wr2[c + 1], pooled[nnC][c + 1], a1);
            }
            float ov = fmaf((a0 + a1) + bb2, iv2, ad2);
            ov = fmaxf(ov, 0.f);
            out[(b * CO + oC) * N_ + bn0 + s * SN + nnC] = ov;
        }

        asm volatile("s_waitcnt lgkmcnt(0)" ::: "memory");
        __builtin_amdgcn_s_barrier();
        __builtin_amdgcn_sched_barrier(0);
    }
}

extern "C" void kernel_launch(void* const* d_in, const int* in_sizes, int n_in,
                              void* d_out, int out_size, void* d_ws, size_t ws_size,
                              hipStream_t stream) {
    const float* points = (const float*)d_in[0];
    const float* imgf   = (const float*)d_in[1];
    const float* dist   = (const float*)d_in[2];
    const int*   idx    = (const int*)  d_in[3];
    const float* w1     = (const float*)d_in[4];
    const float* b1     = (const float*)d_in[5];
    const float* g1     = (const float*)d_in[6];
    const float* be1    = (const float*)d_in[7];
    const float* m1     = (const float*)d_in[8];
    const float* v1     = (const float*)d_in[9];
    const float* w2     = (const float*)d_in[10];
    const float* b2     = (const float*)d_in[11];
    const float* g2     = (const float*)d_in[12];
    const float* be2    = (const float*)d_in[13];
    const float* m2     = (const float*)d_in[14];
    const float* v2     = (const float*)d_in[15];
    float* out          = (float*)d_out;

    pif_mfma_kernel<<<NBLK, 256, 0, stream>>>(
        points, imgf, dist, idx,
        w1, b1, g1, be1, m1, v1,
        w2, b2, g2, be2, m2, v2, out);
}